// Round 4
// baseline (495.026 us; speedup 1.0000x reference)
//
#include <hip/hip_runtime.h>

#define B_  2
#define S_  2048
#define E_  2048
#define H_  16
#define D_  128
#define BS_ (B_*S_)

typedef __bf16 bf16_t;
typedef __bf16 bf16x8 __attribute__((ext_vector_type(8)));
typedef __bf16 bf16x4 __attribute__((ext_vector_type(4)));
typedef float  f32x4  __attribute__((ext_vector_type(4)));

// combined softmax scale: 1/sqrt(128) * log2(e), folded into Q projection
#define QSCALE 0.1275174131003543f

// ---------------- weights-only fp32 -> bf16 convert ----------------
// prefix sums (elements): Wq 4194304 | Wk +262144 | Wv +262144 | Wo +4194304
// total 8912896 = 4 * 256 * 8704
__global__ void cvt_w(const float* __restrict__ s0, const float* __restrict__ s1,
                      const float* __restrict__ s2, const float* __restrict__ s3,
                      bf16_t* d0, bf16_t* d1, bf16_t* d2, bf16_t* d3)
{
    long i = ((long)blockIdx.x * blockDim.x + threadIdx.x) * 4;
    const float* s; bf16_t* d;
    if      (i < 4194304) { s = s0; d = d0; }
    else if (i < 4456448) { s = s1; d = d1; i -= 4194304; }
    else if (i < 4718592) { s = s2; d = d2; i -= 4456448; }
    else                  { s = s3; d = d3; i -= 4718592; }
    float4 v = *(const float4*)(s + i);
    bf16x4 o;
    o[0] = (bf16_t)v.x; o[1] = (bf16_t)v.y; o[2] = (bf16_t)v.z; o[3] = (bf16_t)v.w;
    *(bf16x4*)(d + i) = o;
}

// ============ double-buffered GEMM tile: (A @ W^T + bias) * scale ============
// 128x128 tile, BK=64, ONE barrier per K-step.
// Pipeline: regs hold tile k+1's data while computing tile k from LDS;
// after compute, regs -> LDS (other buffer), issue loads for k+2.
// AF32: A is fp32, converted to bf16 during the reg->LDS store.
// w_n0: row offset into W; c_n0: column offset into C (they differ for the
// V projection which writes cols 128..255 of the interleaved KV buffer).
template<bool AF32>
__device__ __forceinline__ void gemm_tile_db(
    const void* Ap, const bf16_t* __restrict__ W,
    const float* __restrict__ bias,
    float* __restrict__ Cf, bf16_t* __restrict__ Cb,
    int N, int K, float scale, int m0, int w_n0, int c_n0,
    bf16_t* As, bf16_t* Bs)
{
    const int tid  = threadIdx.x;
    const int wave = tid >> 6, lane = tid & 63;
    const int wm = wave >> 1, wn = wave & 1;
    const int lrow = lane & 15, quad = lane >> 4;

    const float*  Af = (const float*)Ap;
    const bf16_t* Ab = (const bf16_t*)Ap;

    float4 arf[8];   // fp32 A prefetch regs (AF32)
    uint4  arb[4];   // bf16 A prefetch regs (!AF32)
    uint4  brb[4];   // bf16 W prefetch regs

    auto loadA = [&](int k0) {
        if constexpr (AF32) {
#pragma unroll
            for (int j = 0; j < 8; ++j) {
                int c = tid + 256 * j, row = c >> 4, col = (c & 15) << 2;
                arf[j] = *(const float4*)(Af + (size_t)(m0 + row) * K + k0 + col);
            }
        } else {
#pragma unroll
            for (int j = 0; j < 4; ++j) {
                int c = tid + 256 * j, row = c >> 3, col = (c & 7) << 3;
                arb[j] = *(const uint4*)(Ab + (size_t)(m0 + row) * K + k0 + col);
            }
        }
    };
    auto loadB = [&](int k0) {
#pragma unroll
        for (int j = 0; j < 4; ++j) {
            int c = tid + 256 * j, row = c >> 3, col = (c & 7) << 3;
            brb[j] = *(const uint4*)(W + (size_t)(w_n0 + row) * K + k0 + col);
        }
    };
    auto storeA = [&](bf16_t* dst) {
        if constexpr (AF32) {
#pragma unroll
            for (int j = 0; j < 8; ++j) {
                int c = tid + 256 * j, row = c >> 4, col = (c & 15) << 2;
                bf16x4 o;
                o[0] = (bf16_t)arf[j].x; o[1] = (bf16_t)arf[j].y;
                o[2] = (bf16_t)arf[j].z; o[3] = (bf16_t)arf[j].w;
                *(bf16x4*)&dst[row * 64 + col] = o;
            }
        } else {
#pragma unroll
            for (int j = 0; j < 4; ++j) {
                int c = tid + 256 * j, row = c >> 3, col = (c & 7) << 3;
                *(uint4*)&dst[row * 64 + col] = arb[j];
            }
        }
    };
    auto storeB = [&](bf16_t* dst) {
#pragma unroll
        for (int j = 0; j < 4; ++j) {
            int c = tid + 256 * j, row = c >> 3, col = (c & 7) << 3;
            *(uint4*)&dst[row * 64 + col] = brb[j];
        }
    };

    f32x4 acc[4][4] = {};

    // prologue: tile 0 -> LDS buf0; tile 1 -> regs
    loadA(0); loadB(0);
    storeA(As); storeB(Bs);
    loadA(64); loadB(64);

    int cur = 0;
    for (int k0 = 0; k0 < K; k0 += 64) {
        __syncthreads();   // buf[cur] writes (prev iter) visible to all waves
        const bf16_t* Ac = As + cur * 8192;
        const bf16_t* Bc = Bs + cur * 8192;
#pragma unroll
        for (int ks = 0; ks < 2; ++ks) {
            bf16x8 af[4], bfr[4];
#pragma unroll
            for (int mt = 0; mt < 4; ++mt)
                af[mt] = *(const bf16x8*)&Ac[(wm * 64 + mt * 16 + lrow) * 64 + ks * 32 + quad * 8];
#pragma unroll
            for (int nt = 0; nt < 4; ++nt)
                bfr[nt] = *(const bf16x8*)&Bc[(wn * 64 + nt * 16 + lrow) * 64 + ks * 32 + quad * 8];
#pragma unroll
            for (int mt = 0; mt < 4; ++mt)
#pragma unroll
                for (int nt = 0; nt < 4; ++nt)
                    acc[mt][nt] = __builtin_amdgcn_mfma_f32_16x16x32_bf16(
                        af[mt], bfr[nt], acc[mt][nt], 0, 0, 0);
        }
        // stage tile k0+64 into the other buffer; prefetch tile k0+128
        if (k0 + 64 < K) {
            storeA(As + (cur ^ 1) * 8192);
            storeB(Bs + (cur ^ 1) * 8192);
            if (k0 + 128 < K) { loadA(k0 + 128); loadB(k0 + 128); }
        }
        cur ^= 1;
    }

#pragma unroll
    for (int mt = 0; mt < 4; ++mt) {
#pragma unroll
        for (int nt = 0; nt < 4; ++nt) {
            int nn = wn * 64 + nt * 16 + lrow;
            float bvv = bias[w_n0 + nn];
            int col = c_n0 + nn;
#pragma unroll
            for (int r = 0; r < 4; ++r) {
                int row = m0 + wm * 64 + mt * 16 + quad * 4 + r;
                float v = (acc[mt][nt][r] + bvv) * scale;
                if (Cf) Cf[(size_t)row * N + col] = v;
                else    Cb[(size_t)row * N + col] = (bf16_t)v;
            }
        }
    }
}

// ---------------- fused Q + K + V projection ----------------
// grid (18, 32): bx<16 -> Q col-tile bx; bx==16 -> K proj; bx==17 -> V proj.
// A (activations) read as fp32 directly; weights bf16 (pre-converted).
__global__ __launch_bounds__(256, 2) void gemm_qkv(
    const float* __restrict__ x, const float* __restrict__ kv,
    const bf16_t* __restrict__ Wq, const bf16_t* __restrict__ Wk,
    const bf16_t* __restrict__ Wv,
    const float* __restrict__ bq, const float* __restrict__ bk,
    const float* __restrict__ bv,
    bf16_t* __restrict__ Qb, bf16_t* __restrict__ KVb)
{
    __shared__ __align__(16) bf16_t As[2 * 8192];
    __shared__ __align__(16) bf16_t Bs[2 * 8192];
    const int m0 = blockIdx.y * 128;
    if (blockIdx.x < 16) {
        int n0 = blockIdx.x * 128;
        gemm_tile_db<true>(x, Wq, bq, nullptr, Qb, E_, E_, QSCALE, m0, n0, n0, As, Bs);
    } else if (blockIdx.x == 16) {
        gemm_tile_db<true>(kv, Wk, bk, nullptr, KVb, 256, E_, 1.0f, m0, 0, 0, As, Bs);
    } else {
        gemm_tile_db<true>(kv, Wv, bv, nullptr, KVb, 256, E_, 1.0f, m0, 0, 128, As, Bs);
    }
}

// ---------------- O projection (fp32 out) ----------------
__global__ __launch_bounds__(256, 2) void gemm_o(
    const bf16_t* __restrict__ A, const bf16_t* __restrict__ W,
    const float* __restrict__ bias, float* __restrict__ Cf)
{
    __shared__ __align__(16) bf16_t As[2 * 8192];
    __shared__ __align__(16) bf16_t Bs[2 * 8192];
    int n0 = blockIdx.x * 128;
    gemm_tile_db<false>(A, W, bias, Cf, nullptr, E_, E_, 1.0f,
                        blockIdx.y * 128, n0, n0, As, Bs);
}

// ---------------- flash-style causal MQA attention (unchanged R3) ----------------
__global__ __launch_bounds__(512, 4) void mqa_attn(
    const bf16_t* __restrict__ Q, const bf16_t* __restrict__ KV,
    bf16_t* __restrict__ O)
{
    __shared__ __align__(16) bf16_t Kt[64][136];
    __shared__ __align__(16) bf16_t Vt[128][72];
    __shared__ __align__(16) bf16_t Pl[8][16][72];

    const int bx = blockIdx.x, h = blockIdx.y, b = blockIdx.z;
    const int qb = b ? bx : (15 - bx);             // complementary pairing
    const int tid = threadIdx.x, wave = tid >> 6, lane = tid & 63;
    const int lrow = lane & 15, quad = lane >> 4;
    const int q0 = qb * 128 + wave * 16;

    const bf16_t* kvp = KV + (size_t)(b * S_) * 256;

    bf16x8 qf[4];
    {
        const bf16_t* qp = Q + ((size_t)(b * S_ + q0 + lrow)) * E_ + h * D_ + quad * 8;
#pragma unroll
        for (int ks = 0; ks < 4; ++ks) qf[ks] = *(const bf16x8*)(qp + ks * 32);
    }

    f32x4 oacc[8] = {};
    float rs[4] = {0.f, 0.f, 0.f, 0.f};

    const int ntiles = 2 * qb + 2;
    bf16x8 kreg[2], vreg[2];

#pragma unroll
    for (int i = 0; i < 2; ++i) {
        int c = tid + 512 * i;
        kreg[i] = *(const bf16x8*)(kvp + (size_t)(c >> 4) * 256 + ((c & 15) << 3));
        vreg[i] = *(const bf16x8*)(kvp + (size_t)(c & 63) * 256 + 128 + ((c >> 6) << 3));
    }

    for (int kt = 0; kt < ntiles; ++kt) {
        const int k_base = kt * 64;
        __syncthreads();
#pragma unroll
        for (int i = 0; i < 2; ++i) {
            int c = tid + 512 * i;
            *(bf16x8*)&Kt[c >> 4][(c & 15) << 3] = kreg[i];
            int n = c & 63, d0 = (c >> 6) << 3;
#pragma unroll
            for (int j = 0; j < 8; ++j) Vt[d0 + j][n] = vreg[i][j];
        }
        __syncthreads();
        if (kt + 1 < ntiles) {
            const int nb = (kt + 1) * 64;
#pragma unroll
            for (int i = 0; i < 2; ++i) {
                int c = tid + 512 * i;
                kreg[i] = *(const bf16x8*)(kvp + (size_t)(nb + (c >> 4)) * 256 + ((c & 15) << 3));
                vreg[i] = *(const bf16x8*)(kvp + (size_t)(nb + (c & 63)) * 256 + 128 + ((c >> 6) << 3));
            }
        }

        if (k_base <= q0 + 15) {
            f32x4 sc[4] = {};
#pragma unroll
            for (int ks = 0; ks < 4; ++ks) {
                bf16x8 a = qf[ks];
#pragma unroll
                for (int c = 0; c < 4; ++c) {
                    bf16x8 kb = *(const bf16x8*)&Kt[c * 16 + lrow][ks * 32 + quad * 8];
                    sc[c] = __builtin_amdgcn_mfma_f32_16x16x32_bf16(a, kb, sc[c], 0, 0, 0);
                }
            }
            const bool diag = (k_base + 63 > q0);
#pragma unroll
            for (int c = 0; c < 4; ++c) {
#pragma unroll
                for (int r = 0; r < 4; ++r) {
                    float s = sc[c][r];
                    if (diag) {
                        int kj = k_base + c * 16 + lrow;
                        int qi = q0 + quad * 4 + r;
                        if (kj > qi) s = -1e30f;
                    }
                    float p = exp2f(fminf(s, 110.f));
                    rs[r] += p;
                    Pl[wave][quad * 4 + r][c * 16 + lrow] = (bf16_t)p;
                }
            }
#pragma unroll
            for (int ks = 0; ks < 2; ++ks) {
                bf16x8 ap = *(const bf16x8*)&Pl[wave][lrow][ks * 32 + quad * 8];
#pragma unroll
                for (int dt = 0; dt < 8; ++dt) {
                    bf16x8 bv = *(const bf16x8*)&Vt[dt * 16 + lrow][ks * 32 + quad * 8];
                    oacc[dt] = __builtin_amdgcn_mfma_f32_16x16x32_bf16(ap, bv, oacc[dt], 0, 0, 0);
                }
            }
        }
    }

#pragma unroll
    for (int off = 8; off >= 1; off >>= 1)
#pragma unroll
        for (int r = 0; r < 4; ++r) rs[r] += __shfl_xor(rs[r], off, 16);
#pragma unroll
    for (int r = 0; r < 4; ++r) {
        float inv = 1.0f / rs[r];
        int row = q0 + quad * 4 + r;
#pragma unroll
        for (int dt = 0; dt < 8; ++dt)
            O[((size_t)(b * S_ + row)) * E_ + h * D_ + dt * 16 + lrow] =
                (bf16_t)(oacc[dt][r] * inv);
    }
}

// ---------------- launch ----------------
extern "C" void kernel_launch(void* const* d_in, const int* in_sizes, int n_in,
                              void* d_out, int out_size, void* d_ws, size_t ws_size,
                              hipStream_t stream)
{
    const float* x   = (const float*)d_in[0];
    const float* kv  = (const float*)d_in[1];
    const float* Wq  = (const float*)d_in[2];
    const float* bq  = (const float*)d_in[3];
    const float* Wk  = (const float*)d_in[4];
    const float* bk  = (const float*)d_in[5];
    const float* Wv  = (const float*)d_in[6];
    const float* bv  = (const float*)d_in[7];
    const float* Wo  = (const float*)d_in[8];
    const float* bo  = (const float*)d_in[9];
    float* out = (float*)d_out;

    bf16_t* p    = (bf16_t*)d_ws;
    bf16_t* Wqb  = p;  p += (size_t)E_ * E_;
    bf16_t* Wkb  = p;  p += (size_t)D_ * E_;
    bf16_t* Wvb  = p;  p += (size_t)D_ * E_;
    bf16_t* Wob  = p;  p += (size_t)E_ * E_;
    bf16_t* Qb   = p;  p += (size_t)BS_ * E_;
    bf16_t* KVb  = p;  p += (size_t)BS_ * 256;
    bf16_t* Ob   = p;  p += (size_t)BS_ * E_;

    // weights to bf16 (small: ~36 MB traffic)
    cvt_w<<<dim3(8704), dim3(256), 0, stream>>>(
        Wq, Wk, Wv, Wo, Wqb, Wkb, Wvb, Wob);

    // fused Q + K + V projections; activations read fp32 directly
    gemm_qkv<<<dim3(18, BS_ / 128), 256, 0, stream>>>(
        x, kv, Wqb, Wkb, Wvb, bq, bk, bv, Qb, KVb);

    // attention
    mqa_attn<<<dim3(S_ / 128, H_, B_), 512, 0, stream>>>(Qb, KVb, Ob);

    // output projection (fp32 out)
    gemm_o<<<dim3(E_ / 128, BS_ / 128), 256, 0, stream>>>(Ob, Wob, bo, out);
}

// Round 5
// 445.245 us; speedup vs baseline: 1.1118x; 1.1118x over previous
//
#include <hip/hip_runtime.h>

#define B_  2
#define S_  2048
#define E_  2048
#define H_  16
#define D_  128
#define BS_ (B_*S_)

typedef __bf16 bf16_t;
typedef __bf16 bf16x8 __attribute__((ext_vector_type(8)));
typedef __bf16 bf16x4 __attribute__((ext_vector_type(4)));
typedef float  f32x4  __attribute__((ext_vector_type(4)));

// softmax scale * log2(e): applied when attention loads fp32 Q
#define QSCALE 0.1275174131003543f

// ---------------- async global->LDS, 16B per lane per call ----------------
__device__ __forceinline__ void gld16(const bf16_t* g, bf16_t* l) {
    __builtin_amdgcn_global_load_lds(
        (const __attribute__((address_space(1))) void*)g,
        (__attribute__((address_space(3))) void*)l,
        16, 0, 0);
}

// ---------------- fused fp32 -> bf16 convert (x, kv, 4 weights) ----------------
// prefix sums: x 8388608 | kv +8388608 | Wq +4194304 | Wk +262144 | Wv +262144
// | Wo +4194304 ; total 25690112 = 1024*25088
__global__ void cvt_all(const float* __restrict__ s0, const float* __restrict__ s1,
                        const float* __restrict__ s2, const float* __restrict__ s3,
                        const float* __restrict__ s4, const float* __restrict__ s5,
                        bf16_t* d0, bf16_t* d1, bf16_t* d2,
                        bf16_t* d3, bf16_t* d4, bf16_t* d5)
{
    long i = ((long)blockIdx.x * blockDim.x + threadIdx.x) * 4;
    const float* s; bf16_t* d;
    if      (i <  8388608) { s = s0; d = d0; }
    else if (i < 16777216) { s = s1; d = d1; i -=  8388608; }
    else if (i < 20971520) { s = s2; d = d2; i -= 16777216; }
    else if (i < 21233664) { s = s3; d = d3; i -= 20971520; }
    else if (i < 21495808) { s = s4; d = d4; i -= 21233664; }
    else                   { s = s5; d = d5; i -= 21495808; }
    float4 v = *(const float4*)(s + i);
    bf16x4 o;
    o[0] = (bf16_t)v.x; o[1] = (bf16_t)v.y; o[2] = (bf16_t)v.z; o[3] = (bf16_t)v.w;
    *(bf16x4*)(d + i) = o;
}

// ========= GEMM tile core: R3-proven m97 structure (gld16, 1 buffer) =========
// Computes acc = A[m0:m0+128, kb:ke] @ W[w_n0:w_n0+128, kb:ke]^T.
// EP==0: atomicAdd fp32 into Cf (+bias if addb) — split-K accumulation.
// EP==1: direct bf16 store into Cb (+dual bias, col>=128 -> biasB).
template<int EP>
__device__ __forceinline__ void gemm_tile_sk(
    const bf16_t* __restrict__ A, const bf16_t* __restrict__ W,
    const float* __restrict__ biasA, const float* __restrict__ biasB,
    float* __restrict__ Cf, bf16_t* __restrict__ Cb,
    int N, int K, int kb, int ke, int m0, int w_n0, int c_n0, bool addb,
    bf16_t* As, bf16_t* Bs)
{
    const int tid  = threadIdx.x;
    const int wave = tid >> 6, lane = tid & 63;
    const int wm = wave >> 1, wn = wave & 1;
    const int lrow = lane & 15, quad = lane >> 4;
    const int r8 = lane >> 3, c8 = (lane & 7) << 3;

    f32x4 acc[4][4] = {};

    for (int k0 = kb; k0 < ke; k0 += 64) {
        __syncthreads();
#pragma unroll
        for (int j = 0; j < 4; ++j) {
            int base = (wave * 4 + j) * 8;                  // wave-uniform LDS base
            gld16(A + (size_t)(m0 + base + r8) * K + k0 + c8, &As[base * 64]);
            gld16(W + (size_t)(w_n0 + base + r8) * K + k0 + c8, &Bs[base * 64]);
        }
        __syncthreads();
#pragma unroll
        for (int ks = 0; ks < 2; ++ks) {
            bf16x8 af[4], bfr[4];
#pragma unroll
            for (int mt = 0; mt < 4; ++mt)
                af[mt] = *(const bf16x8*)&As[(wm * 64 + mt * 16 + lrow) * 64 + ks * 32 + quad * 8];
#pragma unroll
            for (int nt = 0; nt < 4; ++nt)
                bfr[nt] = *(const bf16x8*)&Bs[(wn * 64 + nt * 16 + lrow) * 64 + ks * 32 + quad * 8];
#pragma unroll
            for (int mt = 0; mt < 4; ++mt)
#pragma unroll
                for (int nt = 0; nt < 4; ++nt)
                    acc[mt][nt] = __builtin_amdgcn_mfma_f32_16x16x32_bf16(
                        af[mt], bfr[nt], acc[mt][nt], 0, 0, 0);
        }
    }

#pragma unroll
    for (int mt = 0; mt < 4; ++mt) {
#pragma unroll
        for (int nt = 0; nt < 4; ++nt) {
            int nn = wn * 64 + nt * 16 + lrow;
            int col = c_n0 + nn;
            float bvv;
            if (EP == 0) bvv = addb ? biasA[w_n0 + nn] : 0.0f;
            else         bvv = (biasB && col >= 128) ? biasB[col - 128] : biasA[col];
#pragma unroll
            for (int r = 0; r < 4; ++r) {
                int row = m0 + wm * 64 + mt * 16 + quad * 4 + r;
                float v = acc[mt][nt][r] + bvv;
                if (EP == 0) atomicAdd(&Cf[(size_t)row * N + col], v);
                else         Cb[(size_t)row * N + col] = (bf16_t)v;
            }
        }
    }
}

// ---------------- fused Q + K + V projection, split-K=2 on Q ----------------
// grid (18, 32, 2): bx<16 -> Q col-tile bx, K-half z, atomic fp32 into Qf.
//                   bx==16 (z==0 only) -> K proj;  bx==17 (z==0) -> V proj.
__global__ __launch_bounds__(256) void gemm_qkv(
    const bf16_t* __restrict__ xb, const bf16_t* __restrict__ kvb,
    const bf16_t* __restrict__ Wq, const bf16_t* __restrict__ Wkv,
    const float* __restrict__ bq, const float* __restrict__ bk,
    const float* __restrict__ bv,
    float* __restrict__ Qf, bf16_t* __restrict__ KVb)
{
    if (blockIdx.x >= 16 && blockIdx.z == 1) return;   // KV is unsplit
    __shared__ __align__(16) bf16_t As[8192];
    __shared__ __align__(16) bf16_t Bs[8192];
    const int m0 = blockIdx.y * 128, z = blockIdx.z;
    if (blockIdx.x < 16) {
        int n0 = blockIdx.x * 128;
        gemm_tile_sk<0>(xb, Wq, bq, nullptr, Qf, nullptr, E_, E_,
                        z * 1024, z * 1024 + 1024, m0, n0, n0, z == 0, As, Bs);
    } else {
        int n0 = (blockIdx.x - 16) * 128;   // 0 -> K (Wkv rows 0..127), 128 -> V
        gemm_tile_sk<1>(kvb, Wkv, bk, bv, nullptr, KVb, 256, E_,
                        0, E_, m0, n0, n0, true, As, Bs);
    }
}

// ---------------- O projection, split-K=2, atomic fp32 into d_out ----------------
__global__ __launch_bounds__(256) void gemm_o(
    const bf16_t* __restrict__ A, const bf16_t* __restrict__ W,
    const float* __restrict__ bias, float* __restrict__ Cf)
{
    __shared__ __align__(16) bf16_t As[8192];
    __shared__ __align__(16) bf16_t Bs[8192];
    const int n0 = blockIdx.x * 128, z = blockIdx.z;
    gemm_tile_sk<0>(A, W, bias, nullptr, Cf, nullptr, E_, E_,
                    z * 1024, z * 1024 + 1024, blockIdx.y * 128, n0, n0, z == 0, As, Bs);
}

// ---------------- flash-style causal MQA attention ----------------
// Q now fp32 [B,S,E] (split-K sum, bias included); scale applied at load.
// KV interleaved bf16 [B,S,128K|128V]. O bf16 [B,S,H,D].
__global__ __launch_bounds__(512, 4) void mqa_attn(
    const float* __restrict__ Qf, const bf16_t* __restrict__ KV,
    bf16_t* __restrict__ O)
{
    __shared__ __align__(16) bf16_t Kt[64][136];
    __shared__ __align__(16) bf16_t Vt[128][72];
    __shared__ __align__(16) bf16_t Pl[8][16][72];

    const int bx = blockIdx.x, h = blockIdx.y, b = blockIdx.z;
    const int qb = b ? bx : (15 - bx);             // complementary qb pairing
    const int tid = threadIdx.x, wave = tid >> 6, lane = tid & 63;
    const int lrow = lane & 15, quad = lane >> 4;
    const int q0 = qb * 128 + wave * 16;

    const bf16_t* kvp = KV + (size_t)(b * S_) * 256;

    // Q fragments: fp32 load * QSCALE -> bf16, 16 rows x D=128
    bf16x8 qf[4];
    {
        const float* qp = Qf + ((size_t)(b * S_ + q0 + lrow)) * E_ + h * D_ + quad * 8;
#pragma unroll
        for (int ks = 0; ks < 4; ++ks) {
            float4 a = *(const float4*)(qp + ks * 32);
            float4 c = *(const float4*)(qp + ks * 32 + 4);
            bf16x8 o;
            o[0] = (bf16_t)(a.x * QSCALE); o[1] = (bf16_t)(a.y * QSCALE);
            o[2] = (bf16_t)(a.z * QSCALE); o[3] = (bf16_t)(a.w * QSCALE);
            o[4] = (bf16_t)(c.x * QSCALE); o[5] = (bf16_t)(c.y * QSCALE);
            o[6] = (bf16_t)(c.z * QSCALE); o[7] = (bf16_t)(c.w * QSCALE);
            qf[ks] = o;
        }
    }

    f32x4 oacc[8] = {};
    float rs[4] = {0.f, 0.f, 0.f, 0.f};

    const int ntiles = 2 * qb + 2;
    bf16x8 kreg[2], vreg[2];

#pragma unroll
    for (int i = 0; i < 2; ++i) {
        int c = tid + 512 * i;
        kreg[i] = *(const bf16x8*)(kvp + (size_t)(c >> 4) * 256 + ((c & 15) << 3));
        vreg[i] = *(const bf16x8*)(kvp + (size_t)(c & 63) * 256 + 128 + ((c >> 6) << 3));
    }

    for (int kt = 0; kt < ntiles; ++kt) {
        const int k_base = kt * 64;
        __syncthreads();
#pragma unroll
        for (int i = 0; i < 2; ++i) {
            int c = tid + 512 * i;
            *(bf16x8*)&Kt[c >> 4][(c & 15) << 3] = kreg[i];
            int n = c & 63, d0 = (c >> 6) << 3;
#pragma unroll
            for (int j = 0; j < 8; ++j) Vt[d0 + j][n] = vreg[i][j];
        }
        __syncthreads();
        if (kt + 1 < ntiles) {
            const int nb = (kt + 1) * 64;
#pragma unroll
            for (int i = 0; i < 2; ++i) {
                int c = tid + 512 * i;
                kreg[i] = *(const bf16x8*)(kvp + (size_t)(nb + (c >> 4)) * 256 + ((c & 15) << 3));
                vreg[i] = *(const bf16x8*)(kvp + (size_t)(nb + (c & 63)) * 256 + 128 + ((c >> 6) << 3));
            }
        }

        if (k_base <= q0 + 15) {       // skip fully-masked tiles
            f32x4 sc[4] = {};
#pragma unroll
            for (int ks = 0; ks < 4; ++ks) {
                bf16x8 a = qf[ks];
#pragma unroll
                for (int c = 0; c < 4; ++c) {
                    bf16x8 kb = *(const bf16x8*)&Kt[c * 16 + lrow][ks * 32 + quad * 8];
                    sc[c] = __builtin_amdgcn_mfma_f32_16x16x32_bf16(a, kb, sc[c], 0, 0, 0);
                }
            }
            const bool diag = (k_base + 63 > q0);
#pragma unroll
            for (int c = 0; c < 4; ++c) {
#pragma unroll
                for (int r = 0; r < 4; ++r) {
                    float s = sc[c][r];            // log2-domain score
                    if (diag) {
                        int kj = k_base + c * 16 + lrow;
                        int qi = q0 + quad * 4 + r;
                        if (kj > qi) s = -1e30f;
                    }
                    float p = exp2f(fminf(s, 110.f));
                    rs[r] += p;
                    Pl[wave][quad * 4 + r][c * 16 + lrow] = (bf16_t)p;
                }
            }
#pragma unroll
            for (int ks = 0; ks < 2; ++ks) {
                bf16x8 ap = *(const bf16x8*)&Pl[wave][lrow][ks * 32 + quad * 8];
#pragma unroll
                for (int dt = 0; dt < 8; ++dt) {
                    bf16x8 bv = *(const bf16x8*)&Vt[dt * 16 + lrow][ks * 32 + quad * 8];
                    oacc[dt] = __builtin_amdgcn_mfma_f32_16x16x32_bf16(ap, bv, oacc[dt], 0, 0, 0);
                }
            }
        }
    }

#pragma unroll
    for (int off = 8; off >= 1; off >>= 1)
#pragma unroll
        for (int r = 0; r < 4; ++r) rs[r] += __shfl_xor(rs[r], off, 16);
#pragma unroll
    for (int r = 0; r < 4; ++r) {
        float inv = 1.0f / rs[r];
        int row = q0 + quad * 4 + r;
#pragma unroll
        for (int dt = 0; dt < 8; ++dt)
            O[((size_t)(b * S_ + row)) * E_ + h * D_ + dt * 16 + lrow] =
                (bf16_t)(oacc[dt][r] * inv);
    }
}

// ---------------- launch ----------------
extern "C" void kernel_launch(void* const* d_in, const int* in_sizes, int n_in,
                              void* d_out, int out_size, void* d_ws, size_t ws_size,
                              hipStream_t stream)
{
    const float* x   = (const float*)d_in[0];
    const float* kv  = (const float*)d_in[1];
    const float* Wq  = (const float*)d_in[2];
    const float* bq  = (const float*)d_in[3];
    const float* Wk  = (const float*)d_in[4];
    const float* bk  = (const float*)d_in[5];
    const float* Wv  = (const float*)d_in[6];
    const float* bv  = (const float*)d_in[7];
    const float* Wo  = (const float*)d_in[8];
    const float* bo  = (const float*)d_in[9];
    float* out = (float*)d_out;

    // workspace: 87,031,808 B total (== R1-proven footprint).
    // slotA holds xb during projections, then Ob during attention/O-proj
    // (disjoint lifetimes: xb dead after gemm_qkv; Ob written by attention).
    bf16_t* p    = (bf16_t*)d_ws;
    bf16_t* slA  = p;  p += (size_t)BS_ * E_;      // xb -> Ob
    bf16_t* kvb  = p;  p += (size_t)BS_ * E_;
    bf16_t* Wqb  = p;  p += (size_t)E_ * E_;
    bf16_t* Wkvb = p;  p += (size_t)2 * D_ * E_;
    bf16_t* Wob  = p;  p += (size_t)E_ * E_;
    bf16_t* KVb  = p;  p += (size_t)BS_ * 256;
    float*  Qf   = (float*)p;                      // BS_*E_ fp32 = 32 MB

    // zero split-K accumulators (graph-capture-safe async memset)
    hipMemsetAsync(Qf, 0, (size_t)BS_ * E_ * 4, stream);
    hipMemsetAsync(out, 0, (size_t)out_size * 4, stream);

    cvt_all<<<dim3(25088), dim3(256), 0, stream>>>(
        x, kv, Wq, Wk, Wv, Wo,
        slA, kvb, Wqb, Wkvb, Wkvb + (size_t)D_ * E_, Wob);

    // Q (split-K=2, atomic fp32) + K + V projections
    gemm_qkv<<<dim3(18, BS_ / 128, 2), 256, 0, stream>>>(
        slA, kvb, Wqb, Wkvb, bq, bk, bv, Qf, KVb);

    // attention (reads fp32 Q, scales at load); writes Ob into slotA
    mqa_attn<<<dim3(S_ / 128, H_, B_), 512, 0, stream>>>(Qf, KVb, slA);

    // O projection (split-K=2, atomic fp32 into pre-zeroed d_out)
    gemm_o<<<dim3(E_ / 128, BS_ / 128, 2), 256, 0, stream>>>(slA, Wob, bo, out);
}

// Round 6
// 365.380 us; speedup vs baseline: 1.3548x; 1.2186x over previous
//
#include <hip/hip_runtime.h>

#define B_  2
#define S_  2048
#define E_  2048
#define H_  16
#define D_  128
#define BS_ (B_*S_)

typedef __bf16 bf16_t;
typedef __bf16 bf16x8 __attribute__((ext_vector_type(8)));
typedef __bf16 bf16x4 __attribute__((ext_vector_type(4)));
typedef float  f32x4  __attribute__((ext_vector_type(4)));

// combined softmax scale: 1/sqrt(128) * log2(e), folded into Q projection
#define QSCALE 0.1275174131003543f

// ---------------- async global->LDS, 16B per lane per call ----------------
__device__ __forceinline__ void gld16(const bf16_t* g, bf16_t* l) {
    __builtin_amdgcn_global_load_lds(
        (const __attribute__((address_space(1))) void*)g,
        (__attribute__((address_space(3))) void*)l,
        16, 0, 0);
}

// ---------------- fused fp32 -> bf16 convert (x, kv, 4 weights) ----------------
// prefix sums: x 8388608 | kv +8388608 | Wq +4194304 | Wk +262144 | Wv +262144
// | Wo +4194304 ; total 25690112 = 1024*25088
__global__ void cvt_all(const float* __restrict__ s0, const float* __restrict__ s1,
                        const float* __restrict__ s2, const float* __restrict__ s3,
                        const float* __restrict__ s4, const float* __restrict__ s5,
                        bf16_t* d0, bf16_t* d1, bf16_t* d2,
                        bf16_t* d3, bf16_t* d4, bf16_t* d5)
{
    long i = ((long)blockIdx.x * blockDim.x + threadIdx.x) * 4;
    const float* s; bf16_t* d;
    if      (i <  8388608) { s = s0; d = d0; }
    else if (i < 16777216) { s = s1; d = d1; i -=  8388608; }
    else if (i < 20971520) { s = s2; d = d2; i -= 16777216; }
    else if (i < 21233664) { s = s3; d = d3; i -= 20971520; }
    else if (i < 21495808) { s = s4; d = d4; i -= 21233664; }
    else                   { s = s5; d = d5; i -= 21495808; }
    float4 v = *(const float4*)(s + i);
    bf16x4 o;
    o[0] = (bf16_t)v.x; o[1] = (bf16_t)v.y; o[2] = (bf16_t)v.z; o[3] = (bf16_t)v.w;
    *(bf16x4*)(d + i) = o;
}

// ========== GEMM tile core: LDS-double-buffered gld16 K-loop ==========
// 128x128 tile, BK=64, ONE barrier per K-step. Prefetch goes global->LDS
// directly (zero VGPR cost — the R4 spill lesson). Schedule per step k:
//   barrier (drains tile k's loads, issued one step earlier and overlapped
//   with step k-1's compute) -> issue gld16 for tile k+1 into other buffer
//   -> compute tile k from LDS.
// Safety: barrier at step k+1 also certifies all waves finished reading
// buf[k-1] (lgkmcnt drained) before its gld16 overwrite at step k+1.
// EP==0: fp32 store + bias (O proj). EP==1: bf16 store, dual bias, * scale.
template<int EP>
__device__ __forceinline__ void gemm_tile(
    const bf16_t* __restrict__ A, const bf16_t* __restrict__ W,
    const float* __restrict__ biasA, const float* __restrict__ biasB,
    float* __restrict__ Cf, bf16_t* __restrict__ Cb,
    int N, int K, float scale, int m0, int w_n0, int c_n0,
    bf16_t* As, bf16_t* Bs)
{
    const int tid  = threadIdx.x;
    const int wave = tid >> 6, lane = tid & 63;
    const int wm = wave >> 1, wn = wave & 1;
    const int lrow = lane & 15, quad = lane >> 4;
    const int r8 = lane >> 3, c8 = (lane & 7) << 3;

    f32x4 acc[4][4] = {};

    // stage one 128x64 A-tile + 128x64 W-tile into buffer `buf`
    auto stage = [&](int k0, int buf) {
#pragma unroll
        for (int j = 0; j < 4; ++j) {
            int base = (wave * 4 + j) * 8;   // wave-uniform LDS row base
            gld16(A + (size_t)(m0 + base + r8) * K + k0 + c8,
                  &As[buf * 8192 + base * 64]);
            gld16(W + (size_t)(w_n0 + base + r8) * K + k0 + c8,
                  &Bs[buf * 8192 + base * 64]);
        }
    };

    stage(0, 0);                       // prologue: tile 0 -> buf 0
    const int nk = K >> 6;
    for (int ki = 0; ki < nk; ++ki) {
        __syncthreads();               // drain tile ki's loads (1 step in flight)
        if (ki + 1 < nk) stage((ki + 1) << 6, (ki + 1) & 1);
        const bf16_t* Ac = As + (ki & 1) * 8192;
        const bf16_t* Bc = Bs + (ki & 1) * 8192;
#pragma unroll
        for (int ks = 0; ks < 2; ++ks) {
            bf16x8 af[4], bfr[4];
#pragma unroll
            for (int mt = 0; mt < 4; ++mt)
                af[mt] = *(const bf16x8*)&Ac[(wm * 64 + mt * 16 + lrow) * 64 + ks * 32 + quad * 8];
#pragma unroll
            for (int nt = 0; nt < 4; ++nt)
                bfr[nt] = *(const bf16x8*)&Bc[(wn * 64 + nt * 16 + lrow) * 64 + ks * 32 + quad * 8];
#pragma unroll
            for (int mt = 0; mt < 4; ++mt)
#pragma unroll
                for (int nt = 0; nt < 4; ++nt)
                    acc[mt][nt] = __builtin_amdgcn_mfma_f32_16x16x32_bf16(
                        af[mt], bfr[nt], acc[mt][nt], 0, 0, 0);
        }
    }

#pragma unroll
    for (int mt = 0; mt < 4; ++mt) {
#pragma unroll
        for (int nt = 0; nt < 4; ++nt) {
            int nn = wn * 64 + nt * 16 + lrow;
            int col = c_n0 + nn;
            float bvv = (EP == 1 && biasB && col >= 128) ? biasB[col - 128]
                                                         : biasA[EP == 1 ? col : w_n0 + nn];
#pragma unroll
            for (int r = 0; r < 4; ++r) {
                int row = m0 + wm * 64 + mt * 16 + quad * 4 + r;
                float v = (acc[mt][nt][r] + bvv) * scale;
                if (EP == 0) Cf[(size_t)row * N + col] = v;
                else         Cb[(size_t)row * N + col] = (bf16_t)v;
            }
        }
    }
}

// ---------------- fused Q + K + V projection ----------------
// grid (18, 32): bx<16 -> Q col-tile (scale=QSCALE); bx>=16 -> KV col-tile
// of the stacked Wkv (rows 0..127 = K, 128..255 = V), dual bias.
__global__ __launch_bounds__(256) void gemm_qkv(
    const bf16_t* __restrict__ xb, const bf16_t* __restrict__ kvb,
    const bf16_t* __restrict__ Wq, const bf16_t* __restrict__ Wkv,
    const float* __restrict__ bq, const float* __restrict__ bk,
    const float* __restrict__ bv,
    bf16_t* __restrict__ Qb, bf16_t* __restrict__ KVb)
{
    __shared__ __align__(16) bf16_t As[2 * 8192];
    __shared__ __align__(16) bf16_t Bs[2 * 8192];
    const int m0 = blockIdx.y * 128;
    if (blockIdx.x < 16) {
        int n0 = blockIdx.x * 128;
        gemm_tile<1>(xb, Wq, bq, nullptr, nullptr, Qb, E_, E_, QSCALE,
                     m0, n0, n0, As, Bs);
    } else {
        int n0 = (blockIdx.x - 16) * 128;
        gemm_tile<1>(kvb, Wkv, bk, bv, nullptr, KVb, 256, E_, 1.0f,
                     m0, n0, n0, As, Bs);
    }
}

// ---------------- O projection (fp32 out, direct store) ----------------
__global__ __launch_bounds__(256) void gemm_o(
    const bf16_t* __restrict__ A, const bf16_t* __restrict__ W,
    const float* __restrict__ bias, float* __restrict__ Cf)
{
    __shared__ __align__(16) bf16_t As[2 * 8192];
    __shared__ __align__(16) bf16_t Bs[2 * 8192];
    int n0 = blockIdx.x * 128;
    gemm_tile<0>(A, W, bias, nullptr, Cf, nullptr, E_, E_, 1.0f,
                 blockIdx.y * 128, n0, n0, As, Bs);
}

// ---------------- flash-style causal MQA attention (R3-proven) ----------------
// Q pre-scaled bf16 [B,S,H,D]; KV interleaved bf16 [B,S,128K|128V]; O bf16.
// 8 waves / 128 Q-rows per block; complementary qb pairing balances CU load;
// K/V register-prefetch pipeline; exp2-domain softmax, deferred normalization.
__global__ __launch_bounds__(512, 4) void mqa_attn(
    const bf16_t* __restrict__ Q, const bf16_t* __restrict__ KV,
    bf16_t* __restrict__ O)
{
    __shared__ __align__(16) bf16_t Kt[64][136];
    __shared__ __align__(16) bf16_t Vt[128][72];
    __shared__ __align__(16) bf16_t Pl[8][16][72];

    const int bx = blockIdx.x, h = blockIdx.y, b = blockIdx.z;
    const int qb = b ? bx : (15 - bx);             // complementary pairing
    const int tid = threadIdx.x, wave = tid >> 6, lane = tid & 63;
    const int lrow = lane & 15, quad = lane >> 4;
    const int q0 = qb * 128 + wave * 16;

    const bf16_t* kvp = KV + (size_t)(b * S_) * 256;

    bf16x8 qf[4];
    {
        const bf16_t* qp = Q + ((size_t)(b * S_ + q0 + lrow)) * E_ + h * D_ + quad * 8;
#pragma unroll
        for (int ks = 0; ks < 4; ++ks) qf[ks] = *(const bf16x8*)(qp + ks * 32);
    }

    f32x4 oacc[8] = {};
    float rs[4] = {0.f, 0.f, 0.f, 0.f};

    const int ntiles = 2 * qb + 2;
    bf16x8 kreg[2], vreg[2];

#pragma unroll
    for (int i = 0; i < 2; ++i) {
        int c = tid + 512 * i;
        kreg[i] = *(const bf16x8*)(kvp + (size_t)(c >> 4) * 256 + ((c & 15) << 3));
        vreg[i] = *(const bf16x8*)(kvp + (size_t)(c & 63) * 256 + 128 + ((c >> 6) << 3));
    }

    for (int kt = 0; kt < ntiles; ++kt) {
        const int k_base = kt * 64;
        __syncthreads();
#pragma unroll
        for (int i = 0; i < 2; ++i) {
            int c = tid + 512 * i;
            *(bf16x8*)&Kt[c >> 4][(c & 15) << 3] = kreg[i];
            int n = c & 63, d0 = (c >> 6) << 3;
#pragma unroll
            for (int j = 0; j < 8; ++j) Vt[d0 + j][n] = vreg[i][j];
        }
        __syncthreads();
        if (kt + 1 < ntiles) {
            const int nb = (kt + 1) * 64;
#pragma unroll
            for (int i = 0; i < 2; ++i) {
                int c = tid + 512 * i;
                kreg[i] = *(const bf16x8*)(kvp + (size_t)(nb + (c >> 4)) * 256 + ((c & 15) << 3));
                vreg[i] = *(const bf16x8*)(kvp + (size_t)(nb + (c & 63)) * 256 + 128 + ((c >> 6) << 3));
            }
        }

        if (k_base <= q0 + 15) {       // skip fully-masked tiles
            f32x4 sc[4] = {};
#pragma unroll
            for (int ks = 0; ks < 4; ++ks) {
                bf16x8 a = qf[ks];
#pragma unroll
                for (int c = 0; c < 4; ++c) {
                    bf16x8 kb = *(const bf16x8*)&Kt[c * 16 + lrow][ks * 32 + quad * 8];
                    sc[c] = __builtin_amdgcn_mfma_f32_16x16x32_bf16(a, kb, sc[c], 0, 0, 0);
                }
            }
            const bool diag = (k_base + 63 > q0);
#pragma unroll
            for (int c = 0; c < 4; ++c) {
#pragma unroll
                for (int r = 0; r < 4; ++r) {
                    float s = sc[c][r];            // log2-domain score
                    if (diag) {
                        int kj = k_base + c * 16 + lrow;
                        int qi = q0 + quad * 4 + r;
                        if (kj > qi) s = -1e30f;
                    }
                    float p = exp2f(fminf(s, 110.f));
                    rs[r] += p;
                    Pl[wave][quad * 4 + r][c * 16 + lrow] = (bf16_t)p;
                }
            }
#pragma unroll
            for (int ks = 0; ks < 2; ++ks) {
                bf16x8 ap = *(const bf16x8*)&Pl[wave][lrow][ks * 32 + quad * 8];
#pragma unroll
                for (int dt = 0; dt < 8; ++dt) {
                    bf16x8 bv = *(const bf16x8*)&Vt[dt * 16 + lrow][ks * 32 + quad * 8];
                    oacc[dt] = __builtin_amdgcn_mfma_f32_16x16x32_bf16(ap, bv, oacc[dt], 0, 0, 0);
                }
            }
        }
    }

#pragma unroll
    for (int off = 8; off >= 1; off >>= 1)
#pragma unroll
        for (int r = 0; r < 4; ++r) rs[r] += __shfl_xor(rs[r], off, 16);
#pragma unroll
    for (int r = 0; r < 4; ++r) {
        float inv = 1.0f / rs[r];
        int row = q0 + quad * 4 + r;
#pragma unroll
        for (int dt = 0; dt < 8; ++dt)
            O[((size_t)(b * S_ + row)) * E_ + h * D_ + dt * 16 + lrow] =
                (bf16_t)(oacc[dt][r] * inv);
    }
}

// ---------------- launch ----------------
extern "C" void kernel_launch(void* const* d_in, const int* in_sizes, int n_in,
                              void* d_out, int out_size, void* d_ws, size_t ws_size,
                              hipStream_t stream)
{
    const float* x   = (const float*)d_in[0];
    const float* kv  = (const float*)d_in[1];
    const float* Wq  = (const float*)d_in[2];
    const float* bq  = (const float*)d_in[3];
    const float* Wk  = (const float*)d_in[4];
    const float* bk  = (const float*)d_in[5];
    const float* Wv  = (const float*)d_in[6];
    const float* bv  = (const float*)d_in[7];
    const float* Wo  = (const float*)d_in[8];
    const float* bo  = (const float*)d_in[9];
    float* out = (float*)d_out;

    bf16_t* p    = (bf16_t*)d_ws;
    bf16_t* xb   = p;  p += (size_t)BS_ * E_;
    bf16_t* kvb  = p;  p += (size_t)BS_ * E_;
    bf16_t* Wqb  = p;  p += (size_t)E_ * E_;
    bf16_t* Wkvb = p;  p += (size_t)2 * D_ * E_;
    bf16_t* Wob  = p;  p += (size_t)E_ * E_;
    bf16_t* Qb   = p;  p += (size_t)BS_ * E_;
    bf16_t* KVb  = p;  p += (size_t)BS_ * 256;
    bf16_t* Ob   = p;  p += (size_t)BS_ * E_;

    cvt_all<<<dim3(25088), dim3(256), 0, stream>>>(
        x, kv, Wq, Wk, Wv, Wo,
        xb, kvb, Wqb, Wkvb, Wkvb + (size_t)D_ * E_, Wob);

    // fused Q + K + V projections (LDS-dbuf pipeline)
    gemm_qkv<<<dim3(18, BS_ / 128), 256, 0, stream>>>(
        xb, kvb, Wqb, Wkvb, bq, bk, bv, Qb, KVb);

    // attention
    mqa_attn<<<dim3(S_ / 128, H_, B_), 512, 0, stream>>>(Qb, KVb, Ob);

    // output projection (fp32 out, LDS-dbuf pipeline)
    gemm_o<<<dim3(E_ / 128, BS_ / 128), 256, 0, stream>>>(Ob, Wob, bo, out);
}

// Round 7
// 362.512 us; speedup vs baseline: 1.3655x; 1.0079x over previous
//
#include <hip/hip_runtime.h>

#define B_  2
#define S_  2048
#define E_  2048
#define H_  16
#define D_  128
#define BS_ (B_*S_)

typedef __bf16 bf16_t;
typedef __bf16 bf16x8 __attribute__((ext_vector_type(8)));
typedef __bf16 bf16x4 __attribute__((ext_vector_type(4)));
typedef float  f32x4  __attribute__((ext_vector_type(4)));

// combined softmax scale: 1/sqrt(128) * log2(e), folded into Q projection
#define QSCALE 0.1275174131003543f

// ---------------- async global->LDS, 16B per lane per call ----------------
__device__ __forceinline__ void gld16(const bf16_t* g, bf16_t* l) {
    __builtin_amdgcn_global_load_lds(
        (const __attribute__((address_space(1))) void*)g,
        (__attribute__((address_space(3))) void*)l,
        16, 0, 0);
}

// ---------------- fused fp32 -> bf16 convert (x, kv, 4 weights) ----------------
// prefix sums: x 8388608 | kv +8388608 | Wq +4194304 | Wk +262144 | Wv +262144
// | Wo +4194304 ; total 25690112 = 1024*25088
__global__ void cvt_all(const float* __restrict__ s0, const float* __restrict__ s1,
                        const float* __restrict__ s2, const float* __restrict__ s3,
                        const float* __restrict__ s4, const float* __restrict__ s5,
                        bf16_t* d0, bf16_t* d1, bf16_t* d2,
                        bf16_t* d3, bf16_t* d4, bf16_t* d5)
{
    long i = ((long)blockIdx.x * blockDim.x + threadIdx.x) * 4;
    const float* s; bf16_t* d;
    if      (i <  8388608) { s = s0; d = d0; }
    else if (i < 16777216) { s = s1; d = d1; i -=  8388608; }
    else if (i < 20971520) { s = s2; d = d2; i -= 16777216; }
    else if (i < 21233664) { s = s3; d = d3; i -= 20971520; }
    else if (i < 21495808) { s = s4; d = d4; i -= 21233664; }
    else                   { s = s5; d = d5; i -= 21495808; }
    float4 v = *(const float4*)(s + i);
    bf16x4 o;
    o[0] = (bf16_t)v.x; o[1] = (bf16_t)v.y; o[2] = (bf16_t)v.z; o[3] = (bf16_t)v.w;
    *(bf16x4*)(d + i) = o;
}

// ========== GEMM tile core: 128x64 tile, single-buffer gld16 K-loop ==========
// Smaller tile -> 2x grid -> 4-4.5 blocks/CU co-resident (the m114 TLP regime
// that hides the vmcnt-drain; grid size was the binding constraint at 128x128).
// 4 waves as 2(m)x2(n); per wave 64x32 output = 4x2 fp32x4 frags (32 AGPR).
// LDS 24 KB/block; VGPR ~80 -> LDS/VGPR allow 5+ blocks/CU.
// EP==0: fp32 store + bias. EP==1: bf16 store, dual bias (col>=128 -> biasB).
template<int EP>
__device__ __forceinline__ void gemm_tile64(
    const bf16_t* __restrict__ A, const bf16_t* __restrict__ W,
    const float* __restrict__ biasA, const float* __restrict__ biasB,
    float* __restrict__ Cf, bf16_t* __restrict__ Cb,
    int N, int K, float scale, int m0, int w_n0, int c_n0,
    bf16_t* As, bf16_t* Bs)
{
    const int tid  = threadIdx.x;
    const int wave = tid >> 6, lane = tid & 63;
    const int wm = wave >> 1, wn = wave & 1;
    const int lrow = lane & 15, quad = lane >> 4;
    const int r8 = lane >> 3, c8 = (lane & 7) << 3;

    f32x4 acc[4][2] = {};

    for (int k0 = 0; k0 < K; k0 += 64) {
        __syncthreads();
        // A: 128x64 bf16 = 16 KB, 4 gld16 calls/wave (8 rows each)
#pragma unroll
        for (int j = 0; j < 4; ++j) {
            int base = (wave * 4 + j) * 8;       // wave-uniform LDS row base
            gld16(A + (size_t)(m0 + base + r8) * K + k0 + c8, &As[base * 64]);
        }
        // B: 64x64 bf16 = 8 KB, 2 calls/wave
#pragma unroll
        for (int j = 0; j < 2; ++j) {
            int base = (wave * 2 + j) * 8;
            gld16(W + (size_t)(w_n0 + base + r8) * K + k0 + c8, &Bs[base * 64]);
        }
        __syncthreads();
#pragma unroll
        for (int ks = 0; ks < 2; ++ks) {
            bf16x8 af[4], bfr[2];
#pragma unroll
            for (int mt = 0; mt < 4; ++mt)
                af[mt] = *(const bf16x8*)&As[(wm * 64 + mt * 16 + lrow) * 64 + ks * 32 + quad * 8];
#pragma unroll
            for (int nt = 0; nt < 2; ++nt)
                bfr[nt] = *(const bf16x8*)&Bs[(wn * 32 + nt * 16 + lrow) * 64 + ks * 32 + quad * 8];
#pragma unroll
            for (int mt = 0; mt < 4; ++mt)
#pragma unroll
                for (int nt = 0; nt < 2; ++nt)
                    acc[mt][nt] = __builtin_amdgcn_mfma_f32_16x16x32_bf16(
                        af[mt], bfr[nt], acc[mt][nt], 0, 0, 0);
        }
    }

#pragma unroll
    for (int mt = 0; mt < 4; ++mt) {
#pragma unroll
        for (int nt = 0; nt < 2; ++nt) {
            int nn = wn * 32 + nt * 16 + lrow;
            int col = c_n0 + nn;
            float bvv = (EP == 1 && biasB && col >= 128) ? biasB[col - 128]
                                                         : biasA[col];
#pragma unroll
            for (int r = 0; r < 4; ++r) {
                int row = m0 + wm * 64 + mt * 16 + quad * 4 + r;
                float v = (acc[mt][nt][r] + bvv) * scale;
                if (EP == 0) Cf[(size_t)row * N + col] = v;
                else         Cb[(size_t)row * N + col] = (bf16_t)v;
            }
        }
    }
}

// ---------------- fused Q + K + V projection ----------------
// grid (36, 32): bx<32 -> Q col-tile bx (64 cols, scale QSCALE);
// bx>=32 -> KV col-tile bx-32 of stacked Wkv (rows 0..127 K, 128..255 V).
__global__ __launch_bounds__(256) void gemm_qkv(
    const bf16_t* __restrict__ xb, const bf16_t* __restrict__ kvb,
    const bf16_t* __restrict__ Wq, const bf16_t* __restrict__ Wkv,
    const float* __restrict__ bq, const float* __restrict__ bk,
    const float* __restrict__ bv,
    bf16_t* __restrict__ Qb, bf16_t* __restrict__ KVb)
{
    __shared__ __align__(16) bf16_t As[128 * 64];
    __shared__ __align__(16) bf16_t Bs[64 * 64];
    const int m0 = blockIdx.y * 128;
    if (blockIdx.x < 32) {
        int n0 = blockIdx.x * 64;
        gemm_tile64<1>(xb, Wq, bq, nullptr, nullptr, Qb, E_, E_, QSCALE,
                       m0, n0, n0, As, Bs);
    } else {
        int n0 = (blockIdx.x - 32) * 64;
        gemm_tile64<1>(kvb, Wkv, bk, bv, nullptr, KVb, 256, E_, 1.0f,
                       m0, n0, n0, As, Bs);
    }
}

// ---------------- O projection (fp32 out, direct store) ----------------
__global__ __launch_bounds__(256) void gemm_o(
    const bf16_t* __restrict__ A, const bf16_t* __restrict__ W,
    const float* __restrict__ bias, float* __restrict__ Cf)
{
    __shared__ __align__(16) bf16_t As[128 * 64];
    __shared__ __align__(16) bf16_t Bs[64 * 64];
    int n0 = blockIdx.x * 64;
    gemm_tile64<0>(A, W, bias, nullptr, Cf, nullptr, E_, E_, 1.0f,
                   blockIdx.y * 128, n0, n0, As, Bs);
}

// ---------------- flash-style causal MQA attention (R3-proven) ----------------
// Q pre-scaled bf16 [B,S,H,D]; KV interleaved bf16 [B,S,128K|128V]; O bf16.
// 8 waves / 128 Q-rows per block; complementary qb pairing balances CU load;
// K/V register-prefetch pipeline; exp2-domain softmax, deferred normalization.
__global__ __launch_bounds__(512, 4) void mqa_attn(
    const bf16_t* __restrict__ Q, const bf16_t* __restrict__ KV,
    bf16_t* __restrict__ O)
{
    __shared__ __align__(16) bf16_t Kt[64][136];
    __shared__ __align__(16) bf16_t Vt[128][72];
    __shared__ __align__(16) bf16_t Pl[8][16][72];

    const int bx = blockIdx.x, h = blockIdx.y, b = blockIdx.z;
    const int qb = b ? bx : (15 - bx);             // complementary pairing
    const int tid = threadIdx.x, wave = tid >> 6, lane = tid & 63;
    const int lrow = lane & 15, quad = lane >> 4;
    const int q0 = qb * 128 + wave * 16;

    const bf16_t* kvp = KV + (size_t)(b * S_) * 256;

    bf16x8 qf[4];
    {
        const bf16_t* qp = Q + ((size_t)(b * S_ + q0 + lrow)) * E_ + h * D_ + quad * 8;
#pragma unroll
        for (int ks = 0; ks < 4; ++ks) qf[ks] = *(const bf16x8*)(qp + ks * 32);
    }

    f32x4 oacc[8] = {};
    float rs[4] = {0.f, 0.f, 0.f, 0.f};

    const int ntiles = 2 * qb + 2;
    bf16x8 kreg[2], vreg[2];

#pragma unroll
    for (int i = 0; i < 2; ++i) {
        int c = tid + 512 * i;
        kreg[i] = *(const bf16x8*)(kvp + (size_t)(c >> 4) * 256 + ((c & 15) << 3));
        vreg[i] = *(const bf16x8*)(kvp + (size_t)(c & 63) * 256 + 128 + ((c >> 6) << 3));
    }

    for (int kt = 0; kt < ntiles; ++kt) {
        const int k_base = kt * 64;
        __syncthreads();
#pragma unroll
        for (int i = 0; i < 2; ++i) {
            int c = tid + 512 * i;
            *(bf16x8*)&Kt[c >> 4][(c & 15) << 3] = kreg[i];
            int n = c & 63, d0 = (c >> 6) << 3;
#pragma unroll
            for (int j = 0; j < 8; ++j) Vt[d0 + j][n] = vreg[i][j];
        }
        __syncthreads();
        if (kt + 1 < ntiles) {
            const int nb = (kt + 1) * 64;
#pragma unroll
            for (int i = 0; i < 2; ++i) {
                int c = tid + 512 * i;
                kreg[i] = *(const bf16x8*)(kvp + (size_t)(nb + (c >> 4)) * 256 + ((c & 15) << 3));
                vreg[i] = *(const bf16x8*)(kvp + (size_t)(nb + (c & 63)) * 256 + 128 + ((c >> 6) << 3));
            }
        }

        if (k_base <= q0 + 15) {       // skip fully-masked tiles
            f32x4 sc[4] = {};
#pragma unroll
            for (int ks = 0; ks < 4; ++ks) {
                bf16x8 a = qf[ks];
#pragma unroll
                for (int c = 0; c < 4; ++c) {
                    bf16x8 kb = *(const bf16x8*)&Kt[c * 16 + lrow][ks * 32 + quad * 8];
                    sc[c] = __builtin_amdgcn_mfma_f32_16x16x32_bf16(a, kb, sc[c], 0, 0, 0);
                }
            }
            const bool diag = (k_base + 63 > q0);
#pragma unroll
            for (int c = 0; c < 4; ++c) {
#pragma unroll
                for (int r = 0; r < 4; ++r) {
                    float s = sc[c][r];            // log2-domain score
                    if (diag) {
                        int kj = k_base + c * 16 + lrow;
                        int qi = q0 + quad * 4 + r;
                        if (kj > qi) s = -1e30f;
                    }
                    float p = exp2f(fminf(s, 110.f));
                    rs[r] += p;
                    Pl[wave][quad * 4 + r][c * 16 + lrow] = (bf16_t)p;
                }
            }
#pragma unroll
            for (int ks = 0; ks < 2; ++ks) {
                bf16x8 ap = *(const bf16x8*)&Pl[wave][lrow][ks * 32 + quad * 8];
#pragma unroll
                for (int dt = 0; dt < 8; ++dt) {
                    bf16x8 bv = *(const bf16x8*)&Vt[dt * 16 + lrow][ks * 32 + quad * 8];
                    oacc[dt] = __builtin_amdgcn_mfma_f32_16x16x32_bf16(ap, bv, oacc[dt], 0, 0, 0);
                }
            }
        }
    }

#pragma unroll
    for (int off = 8; off >= 1; off >>= 1)
#pragma unroll
        for (int r = 0; r < 4; ++r) rs[r] += __shfl_xor(rs[r], off, 16);
#pragma unroll
    for (int r = 0; r < 4; ++r) {
        float inv = 1.0f / rs[r];
        int row = q0 + quad * 4 + r;
#pragma unroll
        for (int dt = 0; dt < 8; ++dt)
            O[((size_t)(b * S_ + row)) * E_ + h * D_ + dt * 16 + lrow] =
                (bf16_t)(oacc[dt][r] * inv);
    }
}

// ---------------- launch ----------------
extern "C" void kernel_launch(void* const* d_in, const int* in_sizes, int n_in,
                              void* d_out, int out_size, void* d_ws, size_t ws_size,
                              hipStream_t stream)
{
    const float* x   = (const float*)d_in[0];
    const float* kv  = (const float*)d_in[1];
    const float* Wq  = (const float*)d_in[2];
    const float* bq  = (const float*)d_in[3];
    const float* Wk  = (const float*)d_in[4];
    const float* bk  = (const float*)d_in[5];
    const float* Wv  = (const float*)d_in[6];
    const float* bv  = (const float*)d_in[7];
    const float* Wo  = (const float*)d_in[8];
    const float* bo  = (const float*)d_in[9];
    float* out = (float*)d_out;

    bf16_t* p    = (bf16_t*)d_ws;
    bf16_t* xb   = p;  p += (size_t)BS_ * E_;
    bf16_t* kvb  = p;  p += (size_t)BS_ * E_;
    bf16_t* Wqb  = p;  p += (size_t)E_ * E_;
    bf16_t* Wkvb = p;  p += (size_t)2 * D_ * E_;
    bf16_t* Wob  = p;  p += (size_t)E_ * E_;
    bf16_t* Qb   = p;  p += (size_t)BS_ * E_;
    bf16_t* KVb  = p;  p += (size_t)BS_ * 256;
    bf16_t* Ob   = p;  p += (size_t)BS_ * E_;

    cvt_all<<<dim3(25088), dim3(256), 0, stream>>>(
        x, kv, Wq, Wk, Wv, Wo,
        xb, kvb, Wqb, Wkvb, Wkvb + (size_t)D_ * E_, Wob);

    // fused Q + K + V projections (128x64 tiles, 1152 blocks = 4.5/CU)
    gemm_qkv<<<dim3(36, BS_ / 128), 256, 0, stream>>>(
        xb, kvb, Wqb, Wkvb, bq, bk, bv, Qb, KVb);

    // attention
    mqa_attn<<<dim3(S_ / 128, H_, B_), 512, 0, stream>>>(Qb, KVb, Ob);

    // output projection (128x64 tiles, 1024 blocks = 4/CU)
    gemm_o<<<dim3(E_ / 64, BS_ / 128), 256, 0, stream>>>(Ob, Wob, bo, out);
}